// Round 4
// baseline (409.404 us; speedup 1.0000x reference)
//
#include <hip/hip_runtime.h>

// ---------------------------------------------------------------------------
// Mamba2 layer forward, MI355X (gfx950).
// Sizes: H=2048 DI=4096 N=128 NH=64 P=64 K=4 CH=256 L=4096
// conv_dim = 4352; W_in rows padded 4416 -> 4608 (18 x 256 tiles)
// ---------------------------------------------------------------------------

typedef __bf16 bf16;
typedef __bf16 bf16x8 __attribute__((ext_vector_type(8)));
typedef __bf16 bf16x4 __attribute__((ext_vector_type(4)));
typedef float  f32x4  __attribute__((ext_vector_type(4)));

#define DEV static __device__ __forceinline__

DEV f32x4 mfma16(bf16x8 a, bf16x8 b, f32x4 c) {
  return __builtin_amdgcn_mfma_f32_16x16x32_bf16(a, b, c, 0, 0, 0);
}

DEV void gll16(const bf16* g, bf16* l) {
  __builtin_amdgcn_global_load_lds(
      (const __attribute__((address_space(1))) unsigned int*)g,
      (__attribute__((address_space(3))) unsigned int*)l, 16, 0, 0);
}

#define BAR()   asm volatile("s_barrier" ::: "memory")
#define LGKM0() do { asm volatile("s_waitcnt lgkmcnt(0)" ::: "memory"); \
                     __builtin_amdgcn_sched_barrier(0); } while (0)
#define VMW(n)  asm volatile("s_waitcnt vmcnt(" #n ")" ::: "memory")
#define SCHB()  __builtin_amdgcn_sched_barrier(0)

// ---------------------------------------------------------------------------
// Pipelined bf16 GEMM (m201 geometry), B-transposed: C = A[M][K] * B[N][K]^T
// BM=256 BN=256 BK=64, 8 waves (wave tile 128x64), 2-slot LDS 128KB,
// 4 phases x 16 MFMA per K-tile, chunk-ordered counted vmcnt (4 / 2, never 0),
// XOR-swizzled LDS (pre-swizzled global src + swizzled ds_read; 0 conflicts).
// Split-K via blockIdx.y: half y reads A,B at +y*NT*64, writes C0/C1.
// ---------------------------------------------------------------------------
template <int NT, int LD>
__global__ __launch_bounds__(512, 2) void gemm2k_kernel(
    const bf16* __restrict__ Abase, const bf16* __restrict__ Bbase,
    float* __restrict__ C0, float* __restrict__ C1, int ldc, int ntN) {
  __shared__ __align__(16) bf16 lds[2 * 32768];  // 2 slots x (A 32KB | B 32KB)
  const int tid = threadIdx.x;
  const int wid = tid >> 6, lane = tid & 63;
  const int lrow = lane & 15;
  const int colb = (lane >> 4) * 16;   // 16B k-group within 128B row
  const int xorv = (lrow & 7) << 4;
  const int wm = wid & 1, wn = wid >> 1;
  const int bid = blockIdx.x;
  const int bx = bid / ntN, by = bid % ntN;
  const int row0 = bx * 256, col0 = by * 256;
  const bf16* A = Abase + (size_t)blockIdx.y * (NT * 64);
  const bf16* B = Bbase + (size_t)blockIdx.y * (NT * 64);
  float* C = blockIdx.y ? C1 : C0;

  // staging source (involution of linear LDS dest => swizzled layout)
  const int P = tid * 16;
  const int Lc = P ^ (((P >> 7) & 7) << 4);
  const int srow = Lc >> 7;            // 0..63
  const int selem = (Lc & 127) >> 1;   // 0..63
  const bf16* gA[4];
  const bf16* gB[4];
#pragma unroll
  for (int q = 0; q < 4; ++q) {
    gA[q] = A + (size_t)(row0 + q * 64 + srow) * LD + selem;
    gB[q] = B + (size_t)(col0 + q * 64 + srow) * LD + selem;
  }
  // linear LDS dests (elements): slot s: A chunks q at s*32768+q*4096, B +16384
  auto dA = [&](int s, int q) -> bf16* { return lds + s * 32768 + q * 4096 + tid * 8; };
  auto dB = [&](int s, int q) -> bf16* { return lds + s * 32768 + 16384 + q * 4096 + tid * 8; };

  auto rdA = [&](int s, int m, int ks) -> bf16x8 {
    int row = wm * 128 + m * 16 + lrow;
    int cb = ((ks << 6) | colb) ^ xorv;
    return *(const bf16x8*)((const char*)(lds + s * 32768) + row * 128 + cb);
  };
  auto rdB = [&](int s, int n, int ks) -> bf16x8 {
    int row = wn * 64 + n * 16 + lrow;
    int cb = ((ks << 6) | colb) ^ xorv;
    return *(const bf16x8*)((const char*)(lds + s * 32768 + 16384) + row * 128 + cb);
  };

  f32x4 acc[8][4] = {};
  bf16x8 aF[4][2], bF[4][2];

  // prologue: stage tile 0 in canonical order [B0 B1 B2 B3 A0 A2 A1 A3]
  gll16(gB[0], dB(0, 0)); gll16(gB[1], dB(0, 1));
  gll16(gB[2], dB(0, 2)); gll16(gB[3], dB(0, 3));
  gll16(gA[0], dA(0, 0)); gll16(gA[2], dA(0, 2));
  gll16(gA[1], dA(0, 1)); gll16(gA[3], dA(0, 3));
  VMW(2);   // B*, A0, A2 landed; A1, A3 may remain in flight
  BAR();

  for (int t = 0; t < NT; ++t) {
    const int st = t & 1, ss = st ^ 1;
    const int ko = (t + 1) << 6;
    const bool pf = (t + 1 < NT);
    // ---- P0: read A-lo + B01; stage B0,B1(t+1) ----
#pragma unroll
    for (int m = 0; m < 4; ++m)
#pragma unroll
      for (int ks = 0; ks < 2; ++ks) aF[m][ks] = rdA(st, m, ks);
#pragma unroll
    for (int n = 0; n < 2; ++n)
#pragma unroll
      for (int ks = 0; ks < 2; ++ks) bF[n][ks] = rdB(st, n, ks);
    if (pf) { gll16(gB[0] + ko, dB(ss, 0)); gll16(gB[1] + ko, dB(ss, 1)); }
    BAR(); LGKM0();
    __builtin_amdgcn_s_setprio(1);
#pragma unroll
    for (int m = 0; m < 4; ++m)
#pragma unroll
      for (int n = 0; n < 2; ++n)
#pragma unroll
        for (int ks = 0; ks < 2; ++ks)
          acc[m][n] = mfma16(aF[m][ks], bF[n][ks], acc[m][n]);
    __builtin_amdgcn_s_setprio(0);
    SCHB();
    BAR();
    // ---- P1: read B23; stage B2,B3(t+1); end: vmcnt(4) retires A1,A3(t) ----
#pragma unroll
    for (int n = 2; n < 4; ++n)
#pragma unroll
      for (int ks = 0; ks < 2; ++ks) bF[n][ks] = rdB(st, n, ks);
    if (pf) { gll16(gB[2] + ko, dB(ss, 2)); gll16(gB[3] + ko, dB(ss, 3)); }
    BAR(); LGKM0();
    __builtin_amdgcn_s_setprio(1);
#pragma unroll
    for (int m = 0; m < 4; ++m)
#pragma unroll
      for (int n = 2; n < 4; ++n)
#pragma unroll
        for (int ks = 0; ks < 2; ++ks)
          acc[m][n] = mfma16(aF[m][ks], bF[n][ks], acc[m][n]);
    __builtin_amdgcn_s_setprio(0);
    SCHB();
    if (pf) { VMW(4); } else { VMW(0); }
    BAR();
    // ---- P2: read A-hi (safe: A1,A3 landed + barrier); stage A0,A2(t+1) ----
#pragma unroll
    for (int m = 0; m < 4; ++m)
#pragma unroll
      for (int ks = 0; ks < 2; ++ks) aF[m][ks] = rdA(st, m + 4, ks);
    if (pf) { gll16(gA[0] + ko, dA(ss, 0)); gll16(gA[2] + ko, dA(ss, 2)); }
    BAR(); LGKM0();
    __builtin_amdgcn_s_setprio(1);
#pragma unroll
    for (int m = 0; m < 4; ++m)
#pragma unroll
      for (int n = 2; n < 4; ++n)
#pragma unroll
        for (int ks = 0; ks < 2; ++ks)
          acc[m + 4][n] = mfma16(aF[m][ks], bF[n][ks], acc[m + 4][n]);
    __builtin_amdgcn_s_setprio(0);
    SCHB();
    BAR();
    // ---- P3: no reads; stage A1,A3(t+1); end: vmcnt(2) ----
    if (pf) { gll16(gA[1] + ko, dA(ss, 1)); gll16(gA[3] + ko, dA(ss, 3)); }
    BAR();
    __builtin_amdgcn_s_setprio(1);
#pragma unroll
    for (int m = 0; m < 4; ++m)
#pragma unroll
      for (int n = 0; n < 2; ++n)
#pragma unroll
        for (int ks = 0; ks < 2; ++ks)
          acc[m + 4][n] = mfma16(aF[m][ks], bF[n][ks], acc[m + 4][n]);
    __builtin_amdgcn_s_setprio(0);
    SCHB();
    if (pf) { VMW(2); }
    BAR();
  }
  // epilogue
  const int orow = (lane >> 4) * 4;
#pragma unroll
  for (int m = 0; m < 8; ++m)
#pragma unroll
    for (int n = 0; n < 4; ++n)
#pragma unroll
      for (int i = 0; i < 4; ++i) {
        int r = row0 + wm * 128 + m * 16 + orow + i;
        int c = col0 + wn * 64 + n * 16 + lrow;
        C[(size_t)r * ldc + c] = acc[m][n][i];
      }
}

// ---------------------------------------------------------------------------
__global__ __launch_bounds__(256) void add2_kernel(
    const float* __restrict__ a, const float* __restrict__ b,
    float* __restrict__ o, long n4) {
  long i = (long)blockIdx.x * blockDim.x + threadIdx.x;
  long stride = (long)gridDim.x * blockDim.x;
  for (; i < n4; i += stride) {
    float4 va = ((const float4*)a)[i];
    float4 vb = ((const float4*)b)[i];
    float4 vo = {va.x + vb.x, va.y + vb.y, va.z + vb.z, va.w + vb.w};
    ((float4*)o)[i] = vo;
  }
}

// ---------------------------------------------------------------------------
// Casts (vectorized)
// ---------------------------------------------------------------------------
__global__ __launch_bounds__(256) void cast_f2b_kernel(
    const float* __restrict__ in, bf16* __restrict__ out, long n4) {
  long i = (long)blockIdx.x * blockDim.x + threadIdx.x;
  long stride = (long)gridDim.x * blockDim.x;
  for (; i < n4; i += stride) {
    float4 v = ((const float4*)in)[i];
    bf16x4 o = {(bf16)v.x, (bf16)v.y, (bf16)v.z, (bf16)v.w};
    ((bf16x4*)out)[i] = o;
  }
}

__global__ __launch_bounds__(256) void cast_pad_kernel(
    const float* __restrict__ in, bf16* __restrict__ out, long n4, long valid4) {
  long i = (long)blockIdx.x * blockDim.x + threadIdx.x;
  long stride = (long)gridDim.x * blockDim.x;
  for (; i < n4; i += stride) {
    bf16x4 o = {(bf16)0.f, (bf16)0.f, (bf16)0.f, (bf16)0.f};
    if (i < valid4) {
      float4 v = ((const float4*)in)[i];
      o = bf16x4{(bf16)v.x, (bf16)v.y, (bf16)v.z, (bf16)v.w};
    }
    ((bf16x4*)out)[i] = o;
  }
}

// ---------------------------------------------------------------------------
// dt/cumsum: reads xBCdt = p0 + p1 (stride 4608)
// ---------------------------------------------------------------------------
__global__ __launch_bounds__(256) void dt_scan_kernel(
    const float* __restrict__ xp0, const float* __restrict__ xp1,
    const float* __restrict__ dt_bias, const float* __restrict__ A_log,
    float* __restrict__ dt, float* __restrict__ Acs, float* __restrict__ decayO,
    float* __restrict__ expAcs, float* __restrict__ csum) {
  const int c = blockIdx.x, h = blockIdx.y;
  const int k = threadIdx.x;
  const int t = c * 256 + k;
  __shared__ float buf[256];
  size_t idx = (size_t)t * 4608 + 4352 + h;
  float raw = xp0[idx] + xp1[idx] + dt_bias[h];
  float dtv = raw > 20.f ? raw : log1pf(__expf(raw));
  dtv = fminf(fmaxf(dtv, 0.001f), 100.f);
  dt[(size_t)t * 64 + h] = dtv;
  float dA = -__expf(A_log[h]) * dtv;
  buf[k] = dA;
  __syncthreads();
  for (int off = 1; off < 256; off <<= 1) {
    float add = (k >= off) ? buf[k - off] : 0.f;
    __syncthreads();
    buf[k] += add;
    __syncthreads();
  }
  float v = buf[k];
  float total = buf[255];
  size_t base = (size_t)(c * 64 + h) * 256 + k;
  Acs[base] = v;
  expAcs[base] = __expf(v);
  decayO[base] = __expf(total - v);
  if (k == 0) csum[c * 64 + h] = total;
}

// ---------------------------------------------------------------------------
// Depthwise causal conv (K=4) + bias + SiLU; input = p0 + p1 (stride 4608)
// ---------------------------------------------------------------------------
__global__ __launch_bounds__(256) void conv_kernel(
    const float* __restrict__ xp0, const float* __restrict__ xp1,
    const float* __restrict__ conv_w, const float* __restrict__ conv_b,
    const float* __restrict__ dt, bf16* __restrict__ XS,
    bf16* __restrict__ XDT_T, bf16* __restrict__ Bm, bf16* __restrict__ BT,
    bf16* __restrict__ Cm) {
  const int t0 = blockIdx.x * 64;
  const int c0 = blockIdx.y * 64;
  __shared__ float lin[67 * 64];
  __shared__ bf16 tr[64 * 72];
  const int tid = threadIdx.x;
  for (int idx = tid; idx < 67 * 64; idx += 256) {
    int r = idx >> 6, cc = idx & 63;
    int gt = t0 + r - 3;
    size_t g = (size_t)gt * 4608 + c0 + cc;
    lin[idx] = (gt >= 0) ? (xp0[g] + xp1[g]) : 0.f;
  }
  __syncthreads();
  const int cl = tid & 63, tg = tid >> 6;
  const int ch = c0 + cl;
  const float w0 = conv_w[ch * 4 + 0], w1 = conv_w[ch * 4 + 1];
  const float w2 = conv_w[ch * 4 + 2], w3 = conv_w[ch * 4 + 3];
  const float bb = conv_b[ch];
  float vals[16];
  for (int j = 0; j < 16; ++j) {
    int tl = tg * 16 + j;
    float s = bb + lin[tl * 64 + cl] * w0 + lin[(tl + 1) * 64 + cl] * w1 +
              lin[(tl + 2) * 64 + cl] * w2 + lin[(tl + 3) * 64 + cl] * w3;
    vals[j] = s / (1.f + __expf(-s));
  }
  if (c0 < 4096) {
    const int hh = c0 >> 6;
    for (int j = 0; j < 16; ++j) {
      int t = t0 + tg * 16 + j;
      XS[(size_t)t * 4096 + ch] = (bf16)vals[j];
    }
    __syncthreads();
    for (int j = 0; j < 16; ++j) {
      int tl = tg * 16 + j;
      float dtv = dt[(size_t)(t0 + tl) * 64 + hh];
      tr[cl * 72 + tl] = (bf16)(vals[j] * dtv);
    }
    __syncthreads();
    int p = tid >> 2, toff = (tid & 3) * 16;
    bf16* dst = XDT_T + (size_t)(hh * 64 + p) * 4096 + t0 + toff;
    *(bf16x8*)(dst) = *(const bf16x8*)(tr + p * 72 + toff);
    *(bf16x8*)(dst + 8) = *(const bf16x8*)(tr + p * 72 + toff + 8);
  } else if (c0 < 4224) {
    const int n0 = c0 - 4096;
    for (int j = 0; j < 16; ++j) {
      int t = t0 + tg * 16 + j;
      Bm[(size_t)t * 128 + n0 + cl] = (bf16)vals[j];
    }
    __syncthreads();
    for (int j = 0; j < 16; ++j) tr[cl * 72 + tg * 16 + j] = (bf16)vals[j];
    __syncthreads();
    int p = tid >> 2, toff = (tid & 3) * 16;
    bf16* dst = BT + (size_t)(n0 + p) * 4096 + t0 + toff;
    *(bf16x8*)(dst) = *(const bf16x8*)(tr + p * 72 + toff);
    *(bf16x8*)(dst + 8) = *(const bf16x8*)(tr + p * 72 + toff + 8);
  } else {
    const int n0 = c0 - 4224;
    for (int j = 0; j < 16; ++j) {
      int t = t0 + tg * 16 + j;
      Cm[(size_t)t * 128 + n0 + cl] = (bf16)vals[j];
    }
  }
}

// ---------------------------------------------------------------------------
__global__ __launch_bounds__(256) void gmat_kernel(
    const bf16* __restrict__ Cm, const bf16* __restrict__ Bm,
    float* __restrict__ G) {
  const int c = blockIdx.x, kt = blockIdx.y, st = blockIdx.z;
  const int tid = threadIdx.x;
  const int wave = tid >> 6, lane = tid & 63;
  const int lrow = lane & 15, lk = (lane >> 4) * 8;
  const int wr = (wave >> 1) * 64, wc = (wave & 1) * 64;
  f32x4 acc[4][4] = {};
  for (int kk = 0; kk < 4; ++kk) {
    bf16x8 aF[4], bF[4];
    for (int m = 0; m < 4; ++m)
      aF[m] = *(const bf16x8*)(Cm + (size_t)(c * 256 + kt * 128 + wr + m * 16 + lrow) * 128 + kk * 32 + lk);
    for (int n = 0; n < 4; ++n)
      bF[n] = *(const bf16x8*)(Bm + (size_t)(c * 256 + st * 128 + wc + n * 16 + lrow) * 128 + kk * 32 + lk);
    for (int m = 0; m < 4; ++m)
      for (int n = 0; n < 4; ++n)
        acc[m][n] = mfma16(aF[m], bF[n], acc[m][n]);
  }
  const int orow = (lane >> 4) * 4;
  for (int m = 0; m < 4; ++m)
    for (int n = 0; n < 4; ++n)
      for (int i = 0; i < 4; ++i) {
        int k = kt * 128 + wr + m * 16 + orow + i;
        int s = st * 128 + wc + n * 16 + lrow;
        G[((size_t)c * 256 + k) * 256 + s] = acc[m][n][i];
      }
}

// ---------------------------------------------------------------------------
__global__ __launch_bounds__(256) void states_kernel(
    const bf16* __restrict__ XDT_T, const bf16* __restrict__ BT,
    const float* __restrict__ decayO, float* __restrict__ states) {
  const int c = blockIdx.x, h = blockIdx.y;
  __shared__ bf16 Ap[64 * 264];
  __shared__ float sDec[256];
  const int tid = threadIdx.x;
  const int wave = tid >> 6, lane = tid & 63;
  const int lrow = lane & 15, lk = (lane >> 4) * 8;
  sDec[tid] = decayO[(size_t)(c * 64 + h) * 256 + tid];
  __syncthreads();
  {
    int p = tid >> 2, kb = (tid & 3) * 64;
    const bf16* src = XDT_T + (size_t)(h * 64 + p) * 4096 + c * 256 + kb;
    for (int j = 0; j < 8; ++j) {
      bf16x8 v = *(const bf16x8*)(src + j * 8);
      bf16x8 o;
      for (int i = 0; i < 8; ++i) o[i] = (bf16)((float)v[i] * sDec[kb + j * 8 + i]);
      *(bf16x8*)(Ap + p * 264 + kb + j * 8) = o;
    }
  }
  __syncthreads();
  const int nb = wave * 32;
  f32x4 acc[4][2] = {};
  for (int kk = 0; kk < 8; ++kk) {
    bf16x8 aF[4], bF[2];
    for (int m = 0; m < 4; ++m)
      aF[m] = *(const bf16x8*)(Ap + (m * 16 + lrow) * 264 + kk * 32 + lk);
    for (int n = 0; n < 2; ++n)
      bF[n] = *(const bf16x8*)(BT + (size_t)(nb + n * 16 + lrow) * 4096 + c * 256 + kk * 32 + lk);
    for (int m = 0; m < 4; ++m)
      for (int n = 0; n < 2; ++n)
        acc[m][n] = mfma16(aF[m], bF[n], acc[m][n]);
  }
  float* st = states + (size_t)(c * 64 + h) * 64 * 128;
  const int orow = (lane >> 4) * 4;
  for (int m = 0; m < 4; ++m)
    for (int n = 0; n < 2; ++n)
      for (int i = 0; i < 4; ++i)
        st[(size_t)(m * 16 + orow + i) * 128 + nb + n * 16 + lrow] = acc[m][n][i];
}

// ---------------------------------------------------------------------------
__global__ __launch_bounds__(128) void chunk_rec_kernel(
    const float* __restrict__ states, const float* __restrict__ csum,
    bf16* __restrict__ prev) {
  const int h = blockIdx.x, p = blockIdx.y;
  const int n = threadIdx.x;
  size_t base = (size_t)h * 64 * 128 + (size_t)p * 128 + n;
  float run = 0.f;
  for (int c = 0; c < 16; ++c) {
    size_t idx = (size_t)c * 64 * 64 * 128 + base;
    prev[idx] = (bf16)run;
    run = run * __expf(csum[c * 64 + h]) + states[idx];
  }
}

// ---------------------------------------------------------------------------
// Y = Y_off + Y_diag + XS*D per (chunk, head).
// ---------------------------------------------------------------------------
__global__ __launch_bounds__(256) void ydiag_kernel(
    const bf16* __restrict__ Cm, const bf16* __restrict__ prev,
    const float* __restrict__ G, const float* __restrict__ Acs,
    const float* __restrict__ expAcs, const bf16* __restrict__ XDT_T,
    const bf16* __restrict__ XS, const float* __restrict__ Dp,
    float* __restrict__ Y) {
  const int c = blockIdx.x, h = blockIdx.y;
  __shared__ float sAcs[256];
  __shared__ float sExp[256];
  __shared__ __align__(16) bf16 pv[64 * 136];
  __shared__ __align__(16) bf16 xd[64 * 264];
  const int tid = threadIdx.x;
  const int wave = tid >> 6, lane = tid & 63;
  const int lrow = lane & 15, lk = (lane >> 4) * 8;
  const int wv16 = wave * 16;
  sAcs[tid] = Acs[(size_t)(c * 64 + h) * 256 + tid];
  sExp[tid] = expAcs[(size_t)(c * 64 + h) * 256 + tid];
  {
    int r = tid >> 2, q = (tid & 3) * 32;
    const bf16* src = prev + (size_t)(c * 64 + h) * 8192 + r * 128 + q;
    bf16* dst = pv + r * 136 + q;
    for (int j = 0; j < 4; ++j)
      *(bf16x8*)(dst + j * 8) = *(const bf16x8*)(src + j * 8);
  }
  {
    int r = tid >> 2, q = (tid & 3) * 64;
    const bf16* src = XDT_T + (size_t)(h * 64 + r) * 4096 + c * 256 + q;
    bf16* dst = xd + r * 264 + q;
    for (int j = 0; j < 8; ++j)
      *(bf16x8*)(dst + j * 8) = *(const bf16x8*)(src + j * 8);
  }
  __syncthreads();
  f32x4 acc[4][4] = {};
  __builtin_amdgcn_s_setprio(1);
  for (int kk = 0; kk < 4; ++kk) {
    bf16x8 aF[4], bF[4];
    for (int m = 0; m < 4; ++m)
      aF[m] = *(const bf16x8*)(Cm + (size_t)(c * 256 + m * 64 + wv16 + lrow) * 128 + kk * 32 + lk);
    for (int n = 0; n < 4; ++n)
      bF[n] = *(const bf16x8*)(pv + (n * 16 + lrow) * 136 + kk * 32 + lk);
    for (int m = 0; m < 4; ++m)
      for (int n = 0; n < 4; ++n)
        acc[m][n] = mfma16(aF[m], bF[n], acc[m][n]);
  }
  __builtin_amdgcn_s_setprio(0);
  const int orow = (lane >> 4) * 4;
  for (int m = 0; m < 4; ++m)
    for (int i = 0; i < 4; ++i) {
      float e = sExp[m * 64 + wv16 + orow + i];
      for (int n = 0; n < 4; ++n) acc[m][n][i] *= e;
    }
  const float* Gp = G + (size_t)c * 65536;
  for (int stile = 0; stile < 4; ++stile) {
    const int s0 = stile * 64;
    for (int kk = 0; kk < 2; ++kk) {
      bf16x8 bF[4];
      for (int n = 0; n < 4; ++n)
        bF[n] = *(const bf16x8*)(xd + (n * 16 + lrow) * 264 + s0 + kk * 32 + lk);
      for (int m = 0; m < 4; ++m) {
        if (m * 64 + wv16 + 15 < s0) continue;
        const int row = m * 64 + wv16 + lrow;
        const float ak = sAcs[row];
        const float* grow = Gp + (size_t)row * 256 + s0 + kk * 32 + lk;
        bf16x8 af;
        for (int j = 0; j < 8; ++j) {
          int s = s0 + kk * 32 + lk + j;
          float v = grow[j] * __expf(ak - sAcs[s]);
          if (s > row) v = 0.f;
          af[j] = (bf16)v;
        }
        __builtin_amdgcn_s_setprio(1);
        for (int n = 0; n < 4; ++n)
          acc[m][n] = mfma16(af, bF[n], acc[m][n]);
        __builtin_amdgcn_s_setprio(0);
      }
    }
  }
  const float Dh = Dp[h];
  for (int m = 0; m < 4; ++m)
    for (int n = 0; n < 4; ++n)
      for (int i = 0; i < 4; ++i) {
        int t = c * 256 + m * 64 + wv16 + orow + i;
        int col = h * 64 + n * 16 + lrow;
        float xs = (float)XS[(size_t)t * 4096 + col];
        Y[(size_t)t * 4096 + col] = acc[m][n][i] + xs * Dh;
      }
}

// ---------------------------------------------------------------------------
__global__ __launch_bounds__(256) void rmsnorm_kernel(
    const float* __restrict__ Y, const float* __restrict__ norm_w,
    bf16* __restrict__ out) {
  const int row = blockIdx.x;
  const float4* y4 = (const float4*)(Y + (size_t)row * 4096);
  float4 v[4];
  float ss = 0.f;
  for (int j = 0; j < 4; ++j) {
    v[j] = y4[threadIdx.x + j * 256];
    ss += v[j].x * v[j].x + v[j].y * v[j].y + v[j].z * v[j].z + v[j].w * v[j].w;
  }
  for (int off = 32; off; off >>= 1) ss += __shfl_down(ss, off, 64);
  __shared__ float ws[4];
  if ((threadIdx.x & 63) == 0) ws[threadIdx.x >> 6] = ss;
  __syncthreads();
  float scale = rsqrtf((ws[0] + ws[1] + ws[2] + ws[3]) / 4096.f + 1e-6f);
  for (int j = 0; j < 4; ++j) {
    int col = (threadIdx.x + j * 256) * 4;
    float4 w = *(const float4*)(norm_w + col);
    bf16x4 o = {(bf16)(v[j].x * scale * w.x), (bf16)(v[j].y * scale * w.y),
                (bf16)(v[j].z * scale * w.z), (bf16)(v[j].w * scale * w.w)};
    *(bf16x4*)(out + (size_t)row * 4096 + col) = o;
  }
}

// ---------------------------------------------------------------------------
extern "C" void kernel_launch(void* const* d_in, const int* in_sizes, int n_in,
                              void* d_out, int out_size, void* d_ws, size_t ws_size,
                              hipStream_t stream) {
  const float* x       = (const float*)d_in[0];
  const float* W_in    = (const float*)d_in[1];
  const float* conv_w  = (const float*)d_in[2];
  const float* conv_b  = (const float*)d_in[3];
  const float* dt_bias = (const float*)d_in[4];
  const float* A_log   = (const float*)d_in[5];
  const float* Dp      = (const float*)d_in[6];
  const float* norm_w  = (const float*)d_in[7];
  const float* W_out   = (const float*)d_in[8];

  size_t o = 0;
  char* base = (char*)d_ws;
  auto take = [&](size_t b) {
    char* p = base + o;
    o += (b + 255) & ~(size_t)255;
    return (void*)p;
  };
  bf16*  xb     = (bf16*)take((size_t)4096 * 2048 * 2);    // 16.8 MB
  bf16*  winb   = (bf16*)take((size_t)4608 * 2048 * 2);    // 18.9 MB
  float* xp0    = (float*)take((size_t)4096 * 4608 * 4);   // 75.5 MB (GEMM1 half 0)
  float* xp1    = (float*)take((size_t)4096 * 4608 * 4);   // 75.5 MB (GEMM1 half 1)
  float* dtg    = (float*)take((size_t)4096 * 64 * 4);
  float* Acs    = (float*)take((size_t)4096 * 64 * 4);
  float* decayO = (float*)take((size_t)4096 * 64 * 4);
  float* expA   = (float*)take((size_t)4096 * 64 * 4);
  float* csum   = (float*)take((size_t)16 * 64 * 4);
  bf16*  XS     = (bf16*)take((size_t)4096 * 4096 * 2);    // 33.6 MB
  bf16*  XDT_T  = (bf16*)take((size_t)4096 * 4096 * 2);    // 33.6 MB
  bf16*  Bm     = (bf16*)take((size_t)4096 * 128 * 2);
  bf16*  BT     = (bf16*)take((size_t)4096 * 128 * 2);
  bf16*  Cm     = (bf16*)take((size_t)4096 * 128 * 2);
  // aliases into xp1 (dead after conv): G | states | prev | woutb
  float* G      = (float*)((char*)xp1);                         // 4.19 MB
  float* states = (float*)((char*)xp1 + (size_t)4194304);       // 33.55 MB
  bf16*  prev   = (bf16*)((char*)xp1 + (size_t)37748736);       // 16.78 MB
  bf16*  woutb  = (bf16*)((char*)xp1 + (size_t)54525952);       // 16.78 MB (<=75.5)
  float* Y      = xp0;            // xp0 dead after conv/dt_scan; 67 MB <= 75.5
  bf16*  ynorm  = xb;             // xb+winb dead after GEMM1; 33.6 <= 35.7
  float* p2a    = (float*)XS;     // XS dead after ydiag; 33.55 MB
  float* p2b    = (float*)XDT_T;  // XDT dead after ydiag; 33.55 MB

  // 1) casts for GEMM1
  cast_f2b_kernel<<<2048, 256, 0, stream>>>(x, xb, (long)4096 * 2048 / 4);
  cast_pad_kernel<<<2048, 256, 0, stream>>>(W_in, winb, (long)4608 * 2048 / 4,
                                            (long)4416 * 2048 / 4);
  // 2) GEMM1 split-K2: xp0/xp1 = x @ W_in^T halves (M=4096,N=4608,K=2x1024)
  gemm2k_kernel<16, 2048><<<dim3(288, 2), 512, 0, stream>>>(xb, winb, xp0, xp1,
                                                            4608, 18);
  // 3) dt + per-chunk cumsum (sums partials on the fly)
  dt_scan_kernel<<<dim3(16, 64), 256, 0, stream>>>(xp0, xp1, dt_bias, A_log,
                                                   dtg, Acs, decayO, expA, csum);
  // 4) conv + silu + layout builds (sums partials on the fly)
  conv_kernel<<<dim3(64, 68), 256, 0, stream>>>(xp0, xp1, conv_w, conv_b, dtg,
                                                XS, XDT_T, Bm, BT, Cm);
  // 5) G = C @ B^T per chunk (xp1 now dead -> G/states/prev live there)
  gmat_kernel<<<dim3(16, 2, 2), 256, 0, stream>>>(Cm, Bm, G);
  // 6) intra-chunk states
  states_kernel<<<dim3(16, 64), 256, 0, stream>>>(XDT_T, BT, decayO, states);
  // 7) inter-chunk recurrence -> prev (bf16)
  chunk_rec_kernel<<<dim3(64, 64), 128, 0, stream>>>(states, csum, prev);
  // 8) W_out cast into xp1 tail
  cast_f2b_kernel<<<2048, 256, 0, stream>>>(W_out, woutb, (long)2048 * 4096 / 4);
  // 9) Y = Y_diag + Y_off + XS*D  (writes xp0)
  ydiag_kernel<<<dim3(16, 64), 256, 0, stream>>>(Cm, prev, G, Acs, expA, XDT_T,
                                                 XS, Dp, Y);
  // 10) RMSNorm -> bf16
  rmsnorm_kernel<<<4096, 256, 0, stream>>>(Y, norm_w, ynorm);
  // 11) GEMM2 split-K2: p2a/p2b = ynorm @ W_out^T halves (M=4096,N=2048,K=2x2048)
  gemm2k_kernel<32, 4096><<<dim3(128, 2), 512, 0, stream>>>(ynorm, woutb, p2a,
                                                            p2b, 2048, 8);
  // 12) out = p2a + p2b
  add2_kernel<<<2048, 256, 0, stream>>>(p2a, p2b, (float*)d_out,
                                        (long)4096 * 2048 / 4);
}

// Round 6
// 375.655 us; speedup vs baseline: 1.0898x; 1.0898x over previous
//
#include <hip/hip_runtime.h>

// ---------------------------------------------------------------------------
// Mamba2 layer forward, MI355X (gfx950).
// Sizes: H=2048 DI=4096 N=128 NH=64 P=64 K=4 CH=256 L=4096
// conv_dim = 4352; W_in rows padded 4416 -> 4608 (18 x 256 tiles)
// ---------------------------------------------------------------------------

typedef __bf16 bf16;
typedef __bf16 bf16x8 __attribute__((ext_vector_type(8)));
typedef __bf16 bf16x4 __attribute__((ext_vector_type(4)));
typedef float  f32x4  __attribute__((ext_vector_type(4)));

#define DEV static __device__ __forceinline__

DEV f32x4 mfma16(bf16x8 a, bf16x8 b, f32x4 c) {
  return __builtin_amdgcn_mfma_f32_16x16x32_bf16(a, b, c, 0, 0, 0);
}

DEV void gll16(const bf16* g, bf16* l) {
  __builtin_amdgcn_global_load_lds(
      (const __attribute__((address_space(1))) unsigned int*)g,
      (__attribute__((address_space(3))) unsigned int*)l, 16, 0, 0);
}

#define BAR()   asm volatile("s_barrier" ::: "memory")
#define VMW(n)  asm volatile("s_waitcnt vmcnt(" #n ")" ::: "memory")

// ---------------------------------------------------------------------------
// Pipelined bf16 GEMM, B-transposed: C = A[M][K] * B[N][K]^T  (bf16 C)
// BM=256 BN=256 BK=64, 8 waves (wave tile 128x64), ring-2 LDS (128KB).
// Per K-tile: stage(t+1) issued FIRST (latency hidden under compute), then
// compiler-scheduled ds_reads+MFMA, then VMW(0) BEFORE the single barrier
// (per-wave drain + barrier publish => cross-wave LDS completeness; the
// round-5 bug was VMW after BAR, which races).
// XOR-swizzled LDS (pre-swizzled global src + swizzled ds_read; 0 conflicts).
// Split-K via blockIdx.y. DTC: also write f32 dt columns (4352..4415).
// ---------------------------------------------------------------------------
template <int NT, int LD, bool DTC>
__global__ __launch_bounds__(512) void gemm_kernel(
    const bf16* __restrict__ Abase, const bf16* __restrict__ Bbase,
    bf16* __restrict__ C0, bf16* __restrict__ C1,
    float* __restrict__ dt0, float* __restrict__ dt1, int ldc, int ntN) {
  __shared__ __align__(16) bf16 lds[2 * 32768];  // 2 slots x (A 32KB | B 32KB)
  const int tid = threadIdx.x;
  const int wid = tid >> 6, lane = tid & 63;
  const int lrow = lane & 15;
  const int colb = (lane >> 4) * 16;
  const int xorv = (lrow & 7) << 4;
  const int wm = wid & 1, wn = wid >> 1;
  const int bx = blockIdx.x / ntN, by = blockIdx.x % ntN;
  const int row0 = bx * 256, col0 = by * 256;
  const bf16* A = Abase + (size_t)blockIdx.y * (NT * 64);
  const bf16* B = Bbase + (size_t)blockIdx.y * (NT * 64);
  bf16* C = blockIdx.y ? C1 : C0;

  // staging source (involution of linear LDS dest => swizzled layout)
  const int P = tid * 16;
  const int Lc = P ^ (((P >> 7) & 7) << 4);
  const int srow = Lc >> 7;
  const int selem = (Lc & 127) >> 1;
  const bf16* gA[4];
  const bf16* gB[4];
#pragma unroll
  for (int q = 0; q < 4; ++q) {
    gA[q] = A + (size_t)(row0 + q * 64 + srow) * LD + selem;
    gB[q] = B + (size_t)(col0 + q * 64 + srow) * LD + selem;
  }
  auto stage = [&](int s, int ko) {
#pragma unroll
    for (int q = 0; q < 4; ++q)
      gll16(gA[q] + ko, lds + s * 32768 + q * 4096 + tid * 8);
#pragma unroll
    for (int q = 0; q < 4; ++q)
      gll16(gB[q] + ko, lds + s * 32768 + 16384 + q * 4096 + tid * 8);
  };
  auto rdA = [&](int s, int m, int ks) -> bf16x8 {
    int row = wm * 128 + m * 16 + lrow;
    int cb = ((ks << 6) | colb) ^ xorv;
    return *(const bf16x8*)((const char*)(lds + s * 32768) + row * 128 + cb);
  };
  auto rdB = [&](int s, int n, int ks) -> bf16x8 {
    int row = wn * 64 + n * 16 + lrow;
    int cb = ((ks << 6) | colb) ^ xorv;
    return *(const bf16x8*)((const char*)(lds + s * 32768 + 16384) + row * 128 + cb);
  };

  f32x4 acc[8][4] = {};
  bf16x8 aF[4][2], bF[4][2];

  // prologue: tile 0 fully landed (own drain BEFORE barrier), then publish
  stage(0, 0);
  VMW(0);
  BAR();

  for (int t = 0; t < NT; ++t) {
    const int s = t & 1;
    // issue next tile's loads early; they land during this tile's compute
    if (t + 1 < NT) stage(s ^ 1, (t + 1) * 64);
    // ---- compute: compiler-scheduled reads + MFMA (no intra-tile barriers)
#pragma unroll
    for (int n = 0; n < 4; ++n)
#pragma unroll
      for (int ks = 0; ks < 2; ++ks) bF[n][ks] = rdB(s, n, ks);
#pragma unroll
    for (int m = 0; m < 4; ++m)
#pragma unroll
      for (int ks = 0; ks < 2; ++ks) aF[m][ks] = rdA(s, m, ks);
#pragma unroll
    for (int m = 0; m < 4; ++m)
#pragma unroll
      for (int n = 0; n < 4; ++n)
#pragma unroll
        for (int ks = 0; ks < 2; ++ks)
          acc[m][n] = mfma16(aF[m][ks], bF[n][ks], acc[m][n]);
#pragma unroll
    for (int m = 0; m < 4; ++m)
#pragma unroll
      for (int ks = 0; ks < 2; ++ks) aF[m][ks] = rdA(s, m + 4, ks);
#pragma unroll
    for (int m = 0; m < 4; ++m)
#pragma unroll
      for (int n = 0; n < 4; ++n)
#pragma unroll
        for (int ks = 0; ks < 2; ++ks)
          acc[m + 4][n] = mfma16(aF[m][ks], bF[n][ks], acc[m + 4][n]);
    // ---- own-drain then publish: all waves' tile-(t+1) loads are in LDS
    if (t + 1 < NT) {
      VMW(0);
      BAR();
    }
  }
  // epilogue: bf16 C write (+ optional f32 dt side-channel)
  const int orow = (lane >> 4) * 4;
#pragma unroll
  for (int m = 0; m < 8; ++m)
#pragma unroll
    for (int n = 0; n < 4; ++n)
#pragma unroll
      for (int i = 0; i < 4; ++i) {
        int r = row0 + wm * 128 + m * 16 + orow + i;
        int c = col0 + wn * 64 + n * 16 + lrow;
        C[(size_t)r * ldc + c] = (bf16)acc[m][n][i];
      }
  if (DTC && by == 17 && wn == 0) {
    float* dtp = blockIdx.y ? dt1 : dt0;
#pragma unroll
    for (int m = 0; m < 8; ++m)
#pragma unroll
      for (int n = 0; n < 4; ++n)
#pragma unroll
        for (int i = 0; i < 4; ++i) {
          int r = row0 + wm * 128 + m * 16 + orow + i;
          int h = n * 16 + lrow;  // cols 4352..4415
          dtp[(size_t)r * 64 + h] = acc[m][n][i];
        }
  }
}

// ---------------------------------------------------------------------------
// out = (float)a + (float)b   (bf16 partials -> f32 final)
// ---------------------------------------------------------------------------
__global__ __launch_bounds__(256) void add2b_kernel(
    const bf16* __restrict__ a, const bf16* __restrict__ b,
    float* __restrict__ o, long n8) {
  long i = (long)blockIdx.x * blockDim.x + threadIdx.x;
  long stride = (long)gridDim.x * blockDim.x;
  for (; i < n8; i += stride) {
    bf16x8 va = ((const bf16x8*)a)[i];
    bf16x8 vb = ((const bf16x8*)b)[i];
    float4 o0, o1;
    o0.x = (float)va[0] + (float)vb[0];
    o0.y = (float)va[1] + (float)vb[1];
    o0.z = (float)va[2] + (float)vb[2];
    o0.w = (float)va[3] + (float)vb[3];
    o1.x = (float)va[4] + (float)vb[4];
    o1.y = (float)va[5] + (float)vb[5];
    o1.z = (float)va[6] + (float)vb[6];
    o1.w = (float)va[7] + (float)vb[7];
    ((float4*)o)[i * 2] = o0;
    ((float4*)o)[i * 2 + 1] = o1;
  }
}

// ---------------------------------------------------------------------------
// Casts (vectorized)
// ---------------------------------------------------------------------------
__global__ __launch_bounds__(256) void cast_f2b_kernel(
    const float* __restrict__ in, bf16* __restrict__ out, long n4) {
  long i = (long)blockIdx.x * blockDim.x + threadIdx.x;
  long stride = (long)gridDim.x * blockDim.x;
  for (; i < n4; i += stride) {
    float4 v = ((const float4*)in)[i];
    bf16x4 o = {(bf16)v.x, (bf16)v.y, (bf16)v.z, (bf16)v.w};
    ((bf16x4*)out)[i] = o;
  }
}

__global__ __launch_bounds__(256) void cast_pad_kernel(
    const float* __restrict__ in, bf16* __restrict__ out, long n4, long valid4) {
  long i = (long)blockIdx.x * blockDim.x + threadIdx.x;
  long stride = (long)gridDim.x * blockDim.x;
  for (; i < n4; i += stride) {
    bf16x4 o = {(bf16)0.f, (bf16)0.f, (bf16)0.f, (bf16)0.f};
    if (i < valid4) {
      float4 v = ((const float4*)in)[i];
      o = bf16x4{(bf16)v.x, (bf16)v.y, (bf16)v.z, (bf16)v.w};
    }
    ((bf16x4*)out)[i] = o;
  }
}

// ---------------------------------------------------------------------------
// dt/cumsum from f32 dt side-channel (dt0+dt1)
// ---------------------------------------------------------------------------
__global__ __launch_bounds__(256) void dt_scan_kernel(
    const float* __restrict__ dt0, const float* __restrict__ dt1,
    const float* __restrict__ dt_bias, const float* __restrict__ A_log,
    float* __restrict__ dt, float* __restrict__ Acs, float* __restrict__ decayO,
    float* __restrict__ expAcs, float* __restrict__ csum) {
  const int c = blockIdx.x, h = blockIdx.y;
  const int k = threadIdx.x;
  const int t = c * 256 + k;
  __shared__ float buf[256];
  size_t idx = (size_t)t * 64 + h;
  float raw = dt0[idx] + dt1[idx] + dt_bias[h];
  float dtv = raw > 20.f ? raw : log1pf(__expf(raw));
  dtv = fminf(fmaxf(dtv, 0.001f), 100.f);
  dt[(size_t)t * 64 + h] = dtv;
  float dA = -__expf(A_log[h]) * dtv;
  buf[k] = dA;
  __syncthreads();
  for (int off = 1; off < 256; off <<= 1) {
    float add = (k >= off) ? buf[k - off] : 0.f;
    __syncthreads();
    buf[k] += add;
    __syncthreads();
  }
  float v = buf[k];
  float total = buf[255];
  size_t base = (size_t)(c * 64 + h) * 256 + k;
  Acs[base] = v;
  expAcs[base] = __expf(v);
  decayO[base] = __expf(total - v);
  if (k == 0) csum[c * 64 + h] = total;
}

// ---------------------------------------------------------------------------
// Depthwise causal conv (K=4) + bias + SiLU; input = bf16 p0 + p1 (stride 4608)
// ---------------------------------------------------------------------------
__global__ __launch_bounds__(256) void conv_kernel(
    const bf16* __restrict__ xp0, const bf16* __restrict__ xp1,
    const float* __restrict__ conv_w, const float* __restrict__ conv_b,
    const float* __restrict__ dt, bf16* __restrict__ XS,
    bf16* __restrict__ XDT_T, bf16* __restrict__ Bm, bf16* __restrict__ BT,
    bf16* __restrict__ Cm) {
  const int t0 = blockIdx.x * 64;
  const int c0 = blockIdx.y * 64;
  __shared__ float lin[67 * 64];
  __shared__ bf16 tr[64 * 72];
  const int tid = threadIdx.x;
  for (int idx = tid; idx < 67 * 64; idx += 256) {
    int r = idx >> 6, cc = idx & 63;
    int gt = t0 + r - 3;
    size_t g = (size_t)gt * 4608 + c0 + cc;
    lin[idx] = (gt >= 0) ? ((float)xp0[g] + (float)xp1[g]) : 0.f;
  }
  __syncthreads();
  const int cl = tid & 63, tg = tid >> 6;
  const int ch = c0 + cl;
  const float w0 = conv_w[ch * 4 + 0], w1 = conv_w[ch * 4 + 1];
  const float w2 = conv_w[ch * 4 + 2], w3 = conv_w[ch * 4 + 3];
  const float bb = conv_b[ch];
  float vals[16];
  for (int j = 0; j < 16; ++j) {
    int tl = tg * 16 + j;
    float s = bb + lin[tl * 64 + cl] * w0 + lin[(tl + 1) * 64 + cl] * w1 +
              lin[(tl + 2) * 64 + cl] * w2 + lin[(tl + 3) * 64 + cl] * w3;
    vals[j] = s / (1.f + __expf(-s));
  }
  if (c0 < 4096) {
    const int hh = c0 >> 6;
    for (int j = 0; j < 16; ++j) {
      int t = t0 + tg * 16 + j;
      XS[(size_t)t * 4096 + ch] = (bf16)vals[j];
    }
    __syncthreads();
    for (int j = 0; j < 16; ++j) {
      int tl = tg * 16 + j;
      float dtv = dt[(size_t)(t0 + tl) * 64 + hh];
      tr[cl * 72 + tl] = (bf16)(vals[j] * dtv);
    }
    __syncthreads();
    int p = tid >> 2, toff = (tid & 3) * 16;
    bf16* dst = XDT_T + (size_t)(hh * 64 + p) * 4096 + t0 + toff;
    *(bf16x8*)(dst) = *(const bf16x8*)(tr + p * 72 + toff);
    *(bf16x8*)(dst + 8) = *(const bf16x8*)(tr + p * 72 + toff + 8);
  } else if (c0 < 4224) {
    const int n0 = c0 - 4096;
    for (int j = 0; j < 16; ++j) {
      int t = t0 + tg * 16 + j;
      Bm[(size_t)t * 128 + n0 + cl] = (bf16)vals[j];
    }
    __syncthreads();
    for (int j = 0; j < 16; ++j) tr[cl * 72 + tg * 16 + j] = (bf16)vals[j];
    __syncthreads();
    int p = tid >> 2, toff = (tid & 3) * 16;
    bf16* dst = BT + (size_t)(n0 + p) * 4096 + t0 + toff;
    *(bf16x8*)(dst) = *(const bf16x8*)(tr + p * 72 + toff);
    *(bf16x8*)(dst + 8) = *(const bf16x8*)(tr + p * 72 + toff + 8);
  } else {
    const int n0 = c0 - 4224;
    for (int j = 0; j < 16; ++j) {
      int t = t0 + tg * 16 + j;
      Cm[(size_t)t * 128 + n0 + cl] = (bf16)vals[j];
    }
  }
}

// ---------------------------------------------------------------------------
__global__ __launch_bounds__(256) void gmat_kernel(
    const bf16* __restrict__ Cm, const bf16* __restrict__ Bm,
    float* __restrict__ G) {
  const int c = blockIdx.x, kt = blockIdx.y, st = blockIdx.z;
  const int tid = threadIdx.x;
  const int wave = tid >> 6, lane = tid & 63;
  const int lrow = lane & 15, lk = (lane >> 4) * 8;
  const int wr = (wave >> 1) * 64, wc = (wave & 1) * 64;
  f32x4 acc[4][4] = {};
  for (int kk = 0; kk < 4; ++kk) {
    bf16x8 aF[4], bF[4];
    for (int m = 0; m < 4; ++m)
      aF[m] = *(const bf16x8*)(Cm + (size_t)(c * 256 + kt * 128 + wr + m * 16 + lrow) * 128 + kk * 32 + lk);
    for (int n = 0; n < 4; ++n)
      bF[n] = *(const bf16x8*)(Bm + (size_t)(c * 256 + st * 128 + wc + n * 16 + lrow) * 128 + kk * 32 + lk);
    for (int m = 0; m < 4; ++m)
      for (int n = 0; n < 4; ++n)
        acc[m][n] = mfma16(aF[m], bF[n], acc[m][n]);
  }
  const int orow = (lane >> 4) * 4;
  for (int m = 0; m < 4; ++m)
    for (int n = 0; n < 4; ++n)
      for (int i = 0; i < 4; ++i) {
        int k = kt * 128 + wr + m * 16 + orow + i;
        int s = st * 128 + wc + n * 16 + lrow;
        G[((size_t)c * 256 + k) * 256 + s] = acc[m][n][i];
      }
}

// ---------------------------------------------------------------------------
__global__ __launch_bounds__(256) void states_kernel(
    const bf16* __restrict__ XDT_T, const bf16* __restrict__ BT,
    const float* __restrict__ decayO, float* __restrict__ states) {
  const int c = blockIdx.x, h = blockIdx.y;
  __shared__ bf16 Ap[64 * 264];
  __shared__ float sDec[256];
  const int tid = threadIdx.x;
  const int wave = tid >> 6, lane = tid & 63;
  const int lrow = lane & 15, lk = (lane >> 4) * 8;
  sDec[tid] = decayO[(size_t)(c * 64 + h) * 256 + tid];
  __syncthreads();
  {
    int p = tid >> 2, kb = (tid & 3) * 64;
    const bf16* src = XDT_T + (size_t)(h * 64 + p) * 4096 + c * 256 + kb;
    for (int j = 0; j < 8; ++j) {
      bf16x8 v = *(const bf16x8*)(src + j * 8);
      bf16x8 o;
      for (int i = 0; i < 8; ++i) o[i] = (bf16)((float)v[i] * sDec[kb + j * 8 + i]);
      *(bf16x8*)(Ap + p * 264 + kb + j * 8) = o;
    }
  }
  __syncthreads();
  const int nb = wave * 32;
  f32x4 acc[4][2] = {};
  for (int kk = 0; kk < 8; ++kk) {
    bf16x8 aF[4], bF[2];
    for (int m = 0; m < 4; ++m)
      aF[m] = *(const bf16x8*)(Ap + (m * 16 + lrow) * 264 + kk * 32 + lk);
    for (int n = 0; n < 2; ++n)
      bF[n] = *(const bf16x8*)(BT + (size_t)(nb + n * 16 + lrow) * 4096 + c * 256 + kk * 32 + lk);
    for (int m = 0; m < 4; ++m)
      for (int n = 0; n < 2; ++n)
        acc[m][n] = mfma16(aF[m], bF[n], acc[m][n]);
  }
  float* st = states + (size_t)(c * 64 + h) * 64 * 128;
  const int orow = (lane >> 4) * 4;
  for (int m = 0; m < 4; ++m)
    for (int n = 0; n < 2; ++n)
      for (int i = 0; i < 4; ++i)
        st[(size_t)(m * 16 + orow + i) * 128 + nb + n * 16 + lrow] = acc[m][n][i];
}

// ---------------------------------------------------------------------------
__global__ __launch_bounds__(128) void chunk_rec_kernel(
    const float* __restrict__ states, const float* __restrict__ csum,
    bf16* __restrict__ prev) {
  const int h = blockIdx.x, p = blockIdx.y;
  const int n = threadIdx.x;
  size_t base = (size_t)h * 64 * 128 + (size_t)p * 128 + n;
  float run = 0.f;
  for (int c = 0; c < 16; ++c) {
    size_t idx = (size_t)c * 64 * 64 * 128 + base;
    prev[idx] = (bf16)run;
    run = run * __expf(csum[c * 64 + h]) + states[idx];
  }
}

// ---------------------------------------------------------------------------
// Y = Y_off + Y_diag + XS*D per (chunk, head).
// ---------------------------------------------------------------------------
__global__ __launch_bounds__(256) void ydiag_kernel(
    const bf16* __restrict__ Cm, const bf16* __restrict__ prev,
    const float* __restrict__ G, const float* __restrict__ Acs,
    const float* __restrict__ expAcs, const bf16* __restrict__ XDT_T,
    const bf16* __restrict__ XS, const float* __restrict__ Dp,
    float* __restrict__ Y) {
  const int c = blockIdx.x, h = blockIdx.y;
  __shared__ float sAcs[256];
  __shared__ float sExp[256];
  __shared__ __align__(16) bf16 pv[64 * 136];
  __shared__ __align__(16) bf16 xd[64 * 264];
  const int tid = threadIdx.x;
  const int wave = tid >> 6, lane = tid & 63;
  const int lrow = lane & 15, lk = (lane >> 4) * 8;
  const int wv16 = wave * 16;
  sAcs[tid] = Acs[(size_t)(c * 64 + h) * 256 + tid];
  sExp[tid] = expAcs[(size_t)(c * 64 + h) * 256 + tid];
  {
    int r = tid >> 2, q = (tid & 3) * 32;
    const bf16* src = prev + (size_t)(c * 64 + h) * 8192 + r * 128 + q;
    bf16* dst = pv + r * 136 + q;
    for (int j = 0; j < 4; ++j)
      *(bf16x8*)(dst + j * 8) = *(const bf16x8*)(src + j * 8);
  }
  {
    int r = tid >> 2, q = (tid & 3) * 64;
    const bf16* src = XDT_T + (size_t)(h * 64 + r) * 4096 + c * 256 + q;
    bf16* dst = xd + r * 264 + q;
    for (int j = 0; j < 8; ++j)
      *(bf16x8*)(dst + j * 8) = *(const bf16x8*)(src + j * 8);
  }
  __syncthreads();
  f32x4 acc[4][4] = {};
  __builtin_amdgcn_s_setprio(1);
  for (int kk = 0; kk < 4; ++kk) {
    bf16x8 aF[4], bF[4];
    for (int m = 0; m < 4; ++m)
      aF[m] = *(const bf16x8*)(Cm + (size_t)(c * 256 + m * 64 + wv16 + lrow) * 128 + kk * 32 + lk);
    for (int n = 0; n < 4; ++n)
      bF[n] = *(const bf16x8*)(pv + (n * 16 + lrow) * 136 + kk * 32 + lk);
    for (int m = 0; m < 4; ++m)
      for (int n = 0; n < 4; ++n)
        acc[m][n] = mfma16(aF[m], bF[n], acc[m][n]);
  }
  __builtin_amdgcn_s_setprio(0);
  const int orow = (lane >> 4) * 4;
  for (int m = 0; m < 4; ++m)
    for (int i = 0; i < 4; ++i) {
      float e = sExp[m * 64 + wv16 + orow + i];
      for (int n = 0; n < 4; ++n) acc[m][n][i] *= e;
    }
  const float* Gp = G + (size_t)c * 65536;
  for (int stile = 0; stile < 4; ++stile) {
    const int s0 = stile * 64;
    for (int kk = 0; kk < 2; ++kk) {
      bf16x8 bF[4];
      for (int n = 0; n < 4; ++n)
        bF[n] = *(const bf16x8*)(xd + (n * 16 + lrow) * 264 + s0 + kk * 32 + lk);
      for (int m = 0; m < 4; ++m) {
        if (m * 64 + wv16 + 15 < s0) continue;
        const int row = m * 64 + wv16 + lrow;
        const float ak = sAcs[row];
        const float* grow = Gp + (size_t)row * 256 + s0 + kk * 32 + lk;
        bf16x8 af;
        for (int j = 0; j < 8; ++j) {
          int s = s0 + kk * 32 + lk + j;
          float v = grow[j] * __expf(ak - sAcs[s]);
          if (s > row) v = 0.f;
          af[j] = (bf16)v;
        }
        __builtin_amdgcn_s_setprio(1);
        for (int n = 0; n < 4; ++n)
          acc[m][n] = mfma16(af, bF[n], acc[m][n]);
        __builtin_amdgcn_s_setprio(0);
      }
    }
  }
  const float Dh = Dp[h];
  for (int m = 0; m < 4; ++m)
    for (int n = 0; n < 4; ++n)
      for (int i = 0; i < 4; ++i) {
        int t = c * 256 + m * 64 + wv16 + orow + i;
        int col = h * 64 + n * 16 + lrow;
        float xs = (float)XS[(size_t)t * 4096 + col];
        Y[(size_t)t * 4096 + col] = acc[m][n][i] + xs * Dh;
      }
}

// ---------------------------------------------------------------------------
__global__ __launch_bounds__(256) void rmsnorm_kernel(
    const float* __restrict__ Y, const float* __restrict__ norm_w,
    bf16* __restrict__ out) {
  const int row = blockIdx.x;
  const float4* y4 = (const float4*)(Y + (size_t)row * 4096);
  float4 v[4];
  float ss = 0.f;
  for (int j = 0; j < 4; ++j) {
    v[j] = y4[threadIdx.x + j * 256];
    ss += v[j].x * v[j].x + v[j].y * v[j].y + v[j].z * v[j].z + v[j].w * v[j].w;
  }
  for (int off = 32; off; off >>= 1) ss += __shfl_down(ss, off, 64);
  __shared__ float ws[4];
  if ((threadIdx.x & 63) == 0) ws[threadIdx.x >> 6] = ss;
  __syncthreads();
  float scale = rsqrtf((ws[0] + ws[1] + ws[2] + ws[3]) / 4096.f + 1e-6f);
  for (int j = 0; j < 4; ++j) {
    int col = (threadIdx.x + j * 256) * 4;
    float4 w = *(const float4*)(norm_w + col);
    bf16x4 o = {(bf16)(v[j].x * scale * w.x), (bf16)(v[j].y * scale * w.y),
                (bf16)(v[j].z * scale * w.z), (bf16)(v[j].w * scale * w.w)};
    *(bf16x4*)(out + (size_t)row * 4096 + col) = o;
  }
}

// ---------------------------------------------------------------------------
extern "C" void kernel_launch(void* const* d_in, const int* in_sizes, int n_in,
                              void* d_out, int out_size, void* d_ws, size_t ws_size,
                              hipStream_t stream) {
  const float* x       = (const float*)d_in[0];
  const float* W_in    = (const float*)d_in[1];
  const float* conv_w  = (const float*)d_in[2];
  const float* conv_b  = (const float*)d_in[3];
  const float* dt_bias = (const float*)d_in[4];
  const float* A_log   = (const float*)d_in[5];
  const float* Dp      = (const float*)d_in[6];
  const float* norm_w  = (const float*)d_in[7];
  const float* W_out   = (const float*)d_in[8];

  size_t o = 0;
  char* base = (char*)d_ws;
  auto take = [&](size_t b) {
    char* p = base + o;
    o += (b + 255) & ~(size_t)255;
    return (void*)p;
  };
  bf16*  xb     = (bf16*)take((size_t)4096 * 2048 * 2);    // 16.8 MB
  bf16*  winb   = (bf16*)take((size_t)4608 * 2048 * 2);    // 18.9 MB
  bf16*  xp0b   = (bf16*)take((size_t)4096 * 4608 * 2);    // 37.75 MB
  bf16*  xp1b   = (bf16*)take((size_t)4096 * 4608 * 2);    // 37.75 MB
  float* dt0    = (float*)take((size_t)4096 * 64 * 4);
  float* dt1    = (float*)take((size_t)4096 * 64 * 4);
  float* dtg    = (float*)take((size_t)4096 * 64 * 4);
  float* Acs    = (float*)take((size_t)4096 * 64 * 4);
  float* decayO = (float*)take((size_t)4096 * 64 * 4);
  float* expA   = (float*)take((size_t)4096 * 64 * 4);
  float* csum   = (float*)take((size_t)16 * 64 * 4);
  bf16*  XS     = (bf16*)take((size_t)4096 * 4096 * 2);    // 33.6 MB
  bf16*  XDT_T  = (bf16*)take((size_t)4096 * 4096 * 2);    // 33.6 MB
  bf16*  Bm     = (bf16*)take((size_t)4096 * 128 * 2);
  bf16*  BT     = (bf16*)take((size_t)4096 * 128 * 2);
  bf16*  Cm     = (bf16*)take((size_t)4096 * 128 * 2);
  float* Y      = (float*)take((size_t)4096 * 4096 * 4);   // 67.1 MB
  // aliases into xp0b/xp1b (dead after conv): G | states | prev | woutb
  float* G      = (float*)((char*)xp0b);                        // 4.19 MB
  float* states = (float*)((char*)xp0b + (size_t)4194304);      // 33.55 MB
  bf16*  prev   = (bf16*)((char*)xp0b + (size_t)37748736);      // 16.78 MB
  bf16*  woutb  = (bf16*)((char*)xp0b + (size_t)54525952);      // 16.78 MB
  bf16*  ynorm  = xb;             // xb+winb dead after GEMM1; 33.6 <= 35.7
  bf16*  p2a    = XS;             // XS dead after ydiag
  bf16*  p2b    = XDT_T;          // XDT dead after ydiag

  // 1) casts for GEMM1
  cast_f2b_kernel<<<2048, 256, 0, stream>>>(x, xb, (long)4096 * 2048 / 4);
  cast_pad_kernel<<<2048, 256, 0, stream>>>(W_in, winb, (long)4608 * 2048 / 4,
                                            (long)4416 * 2048 / 4);
  // 2) GEMM1 split-K2 -> bf16 partials + f32 dt side-channel
  gemm_kernel<16, 2048, true><<<dim3(288, 2), 512, 0, stream>>>(
      xb, winb, xp0b, xp1b, dt0, dt1, 4608, 18);
  // 3) dt + per-chunk cumsum (from f32 side-channel)
  dt_scan_kernel<<<dim3(16, 64), 256, 0, stream>>>(dt0, dt1, dt_bias, A_log,
                                                   dtg, Acs, decayO, expA, csum);
  // 4) conv + silu + layout builds (sums bf16 partials)
  conv_kernel<<<dim3(64, 68), 256, 0, stream>>>(xp0b, xp1b, conv_w, conv_b, dtg,
                                                XS, XDT_T, Bm, BT, Cm);
  // 5) G = C @ B^T per chunk (xp0b/xp1b now dead -> aliases live there)
  gmat_kernel<<<dim3(16, 2, 2), 256, 0, stream>>>(Cm, Bm, G);
  // 6) intra-chunk states
  states_kernel<<<dim3(16, 64), 256, 0, stream>>>(XDT_T, BT, decayO, states);
  // 7) inter-chunk recurrence -> prev (bf16)
  chunk_rec_kernel<<<dim3(64, 64), 128, 0, stream>>>(states, csum, prev);
  // 8) W_out cast
  cast_f2b_kernel<<<2048, 256, 0, stream>>>(W_out, woutb, (long)2048 * 4096 / 4);
  // 9) Y = Y_diag + Y_off + XS*D
  ydiag_kernel<<<dim3(16, 64), 256, 0, stream>>>(Cm, prev, G, Acs, expA, XDT_T,
                                                 XS, Dp, Y);
  // 10) RMSNorm -> bf16
  rmsnorm_kernel<<<4096, 256, 0, stream>>>(Y, norm_w, ynorm);
  // 11) GEMM2 split-K2 -> bf16 partials
  gemm_kernel<32, 4096, false><<<dim3(128, 2), 512, 0, stream>>>(
      ynorm, woutb, p2a, p2b, nullptr, nullptr, 2048, 8);
  // 12) out = p2a + p2b (f32)
  add2b_kernel<<<2048, 256, 0, stream>>>(p2a, p2b, (float*)d_out,
                                         (long)4096 * 2048 / 8);
}

// Round 7
// 345.742 us; speedup vs baseline: 1.1841x; 1.0865x over previous
//
#include <hip/hip_runtime.h>

// ---------------------------------------------------------------------------
// Mamba2 layer forward, MI355X (gfx950).
// Sizes: H=2048 DI=4096 N=128 NH=64 P=64 K=4 CH=256 L=4096
// conv_dim = 4352; W_in rows padded 4416 -> 4608 (18 x 256 tiles)
// ---------------------------------------------------------------------------

typedef __bf16 bf16;
typedef __bf16 bf16x8 __attribute__((ext_vector_type(8)));
typedef __bf16 bf16x4 __attribute__((ext_vector_type(4)));
typedef float  f32x4  __attribute__((ext_vector_type(4)));

#define DEV static __device__ __forceinline__

DEV f32x4 mfma16(bf16x8 a, bf16x8 b, f32x4 c) {
  return __builtin_amdgcn_mfma_f32_16x16x32_bf16(a, b, c, 0, 0, 0);
}

DEV void gll16(const bf16* g, bf16* l) {
  __builtin_amdgcn_global_load_lds(
      (const __attribute__((address_space(1))) unsigned int*)g,
      (__attribute__((address_space(3))) unsigned int*)l, 16, 0, 0);
}

#define BAR()   asm volatile("s_barrier" ::: "memory")
#define VMW(n)  asm volatile("s_waitcnt vmcnt(" #n ")" ::: "memory")

// ---------------------------------------------------------------------------
// Pipelined bf16 GEMM, B-transposed: C = A[M][K] * B[N][K]^T  (bf16 C)
// BM=256 BN=256 BK=32, 8 waves (wave tile 128x64), ring-3 LDS (96KB).
// T4 counted-vmcnt ledger (audited): entry outstanding = 8 = {t, t+1};
//   VMW(4) retires tile t (issued 2 iters ago => ~0 wait); BAR publishes;
//   stage(t+2) into slot (t+2)%3 (its readers = compute(t-1), done pre-BAR);
//   compute(t). Tail t=NT-1 uses VMW(0). No drain in steady state.
// LDS layout: [256 rows][32 k] with involution byte ^= ((byte>>7)&3)<<4 --
//   fragment reads hit all 8 16B-slots per 8-row group (conflict-free);
//   staging source = same involution of linear dest (64B global chunks).
// Split-K via blockIdx.y. DTC: also write f32 dt columns (4352..4415).
// ---------------------------------------------------------------------------
template <int NT, int LD, bool DTC>
__global__ __launch_bounds__(512) void gemm_kernel(
    const bf16* __restrict__ Abase, const bf16* __restrict__ Bbase,
    bf16* __restrict__ C0, bf16* __restrict__ C1,
    float* __restrict__ dt0, float* __restrict__ dt1, int ldc, int ntN) {
  __shared__ __align__(16) bf16 lds[3 * 16384];  // 3 slots x (A 16KB | B 16KB)
  const int tid = threadIdx.x;
  const int wid = tid >> 6, lane = tid & 63;
  const int lrow = lane & 15;
  const int lc = lane >> 4;  // 16B k-slot 0..3
  const int wm = wid & 1, wn = wid >> 1;
  const int bx = blockIdx.x / ntN, by = blockIdx.x % ntN;
  const int row0 = bx * 256, col0 = by * 256;
  const bf16* A = Abase + (size_t)blockIdx.y * (NT * 32);
  const bf16* B = Bbase + (size_t)blockIdx.y * (NT * 32);
  bf16* C = blockIdx.y ? C1 : C0;

  // stager source mapping (involution of linear LDS dest)
  const bf16* gA[2];
  const bf16* gB[2];
#pragma unroll
  for (int q = 0; q < 2; ++q) {
    int P = q * 8192 + tid * 16;
    int Bq = P ^ (((P >> 7) & 3) << 4);
    int srow = Bq >> 6;          // 0..255
    int selem = (Bq & 63) >> 1;  // 0..31
    gA[q] = A + (size_t)(row0 + srow) * LD + selem;
    gB[q] = B + (size_t)(col0 + srow) * LD + selem;
  }
  auto stage = [&](int s, int ko) {
    bf16* sl = lds + s * 16384;
    gll16(gA[0] + ko, sl + tid * 8);
    gll16(gA[1] + ko, sl + 4096 + tid * 8);
    gll16(gB[0] + ko, sl + 8192 + tid * 8);
    gll16(gB[1] + ko, sl + 12288 + tid * 8);
  };
  auto rdA = [&](int s, int m) -> bf16x8 {
    int row = wm * 128 + m * 16 + lrow;
    int off = row * 64 + ((lc ^ ((row >> 1) & 3)) << 4);
    return *(const bf16x8*)((const char*)(lds + s * 16384) + off);
  };
  auto rdB = [&](int s, int n) -> bf16x8 {
    int row = wn * 64 + n * 16 + lrow;
    int off = row * 64 + ((lc ^ ((row >> 1) & 3)) << 4);
    return *(const bf16x8*)((const char*)(lds + s * 16384) + 16384 + off);
  };

  f32x4 acc[8][4] = {};
  // prologue: tiles 0 and 1 in flight (8 outstanding)
  stage(0, 0);
  stage(1, 32);
  int rs = 0, ws = 2;
  for (int t = 0; t < NT; ++t) {
    if (t + 1 < NT) { VMW(4); } else { VMW(0); }
    BAR();
    if (t + 2 < NT) stage(ws, (t + 2) * 32);
    bf16x8 b0 = rdB(rs, 0), b1 = rdB(rs, 1), b2 = rdB(rs, 2), b3 = rdB(rs, 3);
#pragma unroll
    for (int m = 0; m < 8; ++m) {
      bf16x8 a = rdA(rs, m);
      acc[m][0] = mfma16(a, b0, acc[m][0]);
      acc[m][1] = mfma16(a, b1, acc[m][1]);
      acc[m][2] = mfma16(a, b2, acc[m][2]);
      acc[m][3] = mfma16(a, b3, acc[m][3]);
    }
    rs = (rs == 2) ? 0 : rs + 1;
    ws = (ws == 2) ? 0 : ws + 1;
  }
  // epilogue: bf16 C write (+ optional f32 dt side-channel)
  const int orow = lc * 4;
#pragma unroll
  for (int m = 0; m < 8; ++m)
#pragma unroll
    for (int n = 0; n < 4; ++n)
#pragma unroll
      for (int i = 0; i < 4; ++i) {
        int r = row0 + wm * 128 + m * 16 + orow + i;
        int c = col0 + wn * 64 + n * 16 + lrow;
        C[(size_t)r * ldc + c] = (bf16)acc[m][n][i];
      }
  if (DTC && by == 17 && wn == 0) {
    float* dtp = blockIdx.y ? dt1 : dt0;
#pragma unroll
    for (int m = 0; m < 8; ++m)
#pragma unroll
      for (int n = 0; n < 4; ++n)
#pragma unroll
        for (int i = 0; i < 4; ++i) {
          int r = row0 + wm * 128 + m * 16 + orow + i;
          int h = n * 16 + lrow;  // cols 4352..4415
          dtp[(size_t)r * 64 + h] = acc[m][n][i];
        }
  }
}

// ---------------------------------------------------------------------------
// out = (float)a + (float)b   (bf16 partials -> f32 final)
// ---------------------------------------------------------------------------
__global__ __launch_bounds__(256) void add2b_kernel(
    const bf16* __restrict__ a, const bf16* __restrict__ b,
    float* __restrict__ o, long n8) {
  long i = (long)blockIdx.x * blockDim.x + threadIdx.x;
  long stride = (long)gridDim.x * blockDim.x;
  for (; i < n8; i += stride) {
    bf16x8 va = ((const bf16x8*)a)[i];
    bf16x8 vb = ((const bf16x8*)b)[i];
    float4 o0, o1;
    o0.x = (float)va[0] + (float)vb[0];
    o0.y = (float)va[1] + (float)vb[1];
    o0.z = (float)va[2] + (float)vb[2];
    o0.w = (float)va[3] + (float)vb[3];
    o1.x = (float)va[4] + (float)vb[4];
    o1.y = (float)va[5] + (float)vb[5];
    o1.z = (float)va[6] + (float)vb[6];
    o1.w = (float)va[7] + (float)vb[7];
    ((float4*)o)[i * 2] = o0;
    ((float4*)o)[i * 2 + 1] = o1;
  }
}

// ---------------------------------------------------------------------------
// Casts (vectorized)
// ---------------------------------------------------------------------------
__global__ __launch_bounds__(256) void cast_f2b_kernel(
    const float* __restrict__ in, bf16* __restrict__ out, long n4) {
  long i = (long)blockIdx.x * blockDim.x + threadIdx.x;
  long stride = (long)gridDim.x * blockDim.x;
  for (; i < n4; i += stride) {
    float4 v = ((const float4*)in)[i];
    bf16x4 o = {(bf16)v.x, (bf16)v.y, (bf16)v.z, (bf16)v.w};
    ((bf16x4*)out)[i] = o;
  }
}

__global__ __launch_bounds__(256) void cast_pad_kernel(
    const float* __restrict__ in, bf16* __restrict__ out, long n4, long valid4) {
  long i = (long)blockIdx.x * blockDim.x + threadIdx.x;
  long stride = (long)gridDim.x * blockDim.x;
  for (; i < n4; i += stride) {
    bf16x4 o = {(bf16)0.f, (bf16)0.f, (bf16)0.f, (bf16)0.f};
    if (i < valid4) {
      float4 v = ((const float4*)in)[i];
      o = bf16x4{(bf16)v.x, (bf16)v.y, (bf16)v.z, (bf16)v.w};
    }
    ((bf16x4*)out)[i] = o;
  }
}

// ---------------------------------------------------------------------------
// dt/cumsum from f32 dt side-channel (dt0+dt1)
// ---------------------------------------------------------------------------
__global__ __launch_bounds__(256) void dt_scan_kernel(
    const float* __restrict__ dt0, const float* __restrict__ dt1,
    const float* __restrict__ dt_bias, const float* __restrict__ A_log,
    float* __restrict__ dt, float* __restrict__ Acs, float* __restrict__ decayO,
    float* __restrict__ expAcs, float* __restrict__ csum) {
  const int c = blockIdx.x, h = blockIdx.y;
  const int k = threadIdx.x;
  const int t = c * 256 + k;
  __shared__ float buf[256];
  size_t idx = (size_t)t * 64 + h;
  float raw = dt0[idx] + dt1[idx] + dt_bias[h];
  float dtv = raw > 20.f ? raw : log1pf(__expf(raw));
  dtv = fminf(fmaxf(dtv, 0.001f), 100.f);
  dt[(size_t)t * 64 + h] = dtv;
  float dA = -__expf(A_log[h]) * dtv;
  buf[k] = dA;
  __syncthreads();
  for (int off = 1; off < 256; off <<= 1) {
    float add = (k >= off) ? buf[k - off] : 0.f;
    __syncthreads();
    buf[k] += add;
    __syncthreads();
  }
  float v = buf[k];
  float total = buf[255];
  size_t base = (size_t)(c * 64 + h) * 256 + k;
  Acs[base] = v;
  expAcs[base] = __expf(v);
  decayO[base] = __expf(total - v);
  if (k == 0) csum[c * 64 + h] = total;
}

// ---------------------------------------------------------------------------
// Depthwise causal conv (K=4) + bias + SiLU; input = bf16 p0 + p1 (stride 4608)
// ---------------------------------------------------------------------------
__global__ __launch_bounds__(256) void conv_kernel(
    const bf16* __restrict__ xp0, const bf16* __restrict__ xp1,
    const float* __restrict__ conv_w, const float* __restrict__ conv_b,
    const float* __restrict__ dt, bf16* __restrict__ XS,
    bf16* __restrict__ XDT_T, bf16* __restrict__ Bm, bf16* __restrict__ BT,
    bf16* __restrict__ Cm) {
  const int t0 = blockIdx.x * 64;
  const int c0 = blockIdx.y * 64;
  __shared__ float lin[67 * 64];
  __shared__ bf16 tr[64 * 72];
  const int tid = threadIdx.x;
  for (int idx = tid; idx < 67 * 64; idx += 256) {
    int r = idx >> 6, cc = idx & 63;
    int gt = t0 + r - 3;
    size_t g = (size_t)gt * 4608 + c0 + cc;
    lin[idx] = (gt >= 0) ? ((float)xp0[g] + (float)xp1[g]) : 0.f;
  }
  __syncthreads();
  const int cl = tid & 63, tg = tid >> 6;
  const int ch = c0 + cl;
  const float w0 = conv_w[ch * 4 + 0], w1 = conv_w[ch * 4 + 1];
  const float w2 = conv_w[ch * 4 + 2], w3 = conv_w[ch * 4 + 3];
  const float bb = conv_b[ch];
  float vals[16];
  for (int j = 0; j < 16; ++j) {
    int tl = tg * 16 + j;
    float s = bb + lin[tl * 64 + cl] * w0 + lin[(tl + 1) * 64 + cl] * w1 +
              lin[(tl + 2) * 64 + cl] * w2 + lin[(tl + 3) * 64 + cl] * w3;
    vals[j] = s / (1.f + __expf(-s));
  }
  if (c0 < 4096) {
    const int hh = c0 >> 6;
    for (int j = 0; j < 16; ++j) {
      int t = t0 + tg * 16 + j;
      XS[(size_t)t * 4096 + ch] = (bf16)vals[j];
    }
    __syncthreads();
    for (int j = 0; j < 16; ++j) {
      int tl = tg * 16 + j;
      float dtv = dt[(size_t)(t0 + tl) * 64 + hh];
      tr[cl * 72 + tl] = (bf16)(vals[j] * dtv);
    }
    __syncthreads();
    int p = tid >> 2, toff = (tid & 3) * 16;
    bf16* dst = XDT_T + (size_t)(hh * 64 + p) * 4096 + t0 + toff;
    *(bf16x8*)(dst) = *(const bf16x8*)(tr + p * 72 + toff);
    *(bf16x8*)(dst + 8) = *(const bf16x8*)(tr + p * 72 + toff + 8);
  } else if (c0 < 4224) {
    const int n0 = c0 - 4096;
    for (int j = 0; j < 16; ++j) {
      int t = t0 + tg * 16 + j;
      Bm[(size_t)t * 128 + n0 + cl] = (bf16)vals[j];
    }
    __syncthreads();
    for (int j = 0; j < 16; ++j) tr[cl * 72 + tg * 16 + j] = (bf16)vals[j];
    __syncthreads();
    int p = tid >> 2, toff = (tid & 3) * 16;
    bf16* dst = BT + (size_t)(n0 + p) * 4096 + t0 + toff;
    *(bf16x8*)(dst) = *(const bf16x8*)(tr + p * 72 + toff);
    *(bf16x8*)(dst + 8) = *(const bf16x8*)(tr + p * 72 + toff + 8);
  } else {
    const int n0 = c0 - 4224;
    for (int j = 0; j < 16; ++j) {
      int t = t0 + tg * 16 + j;
      Cm[(size_t)t * 128 + n0 + cl] = (bf16)vals[j];
    }
  }
}

// ---------------------------------------------------------------------------
// G[c][k][s] (bf16) = sum_n Cm[c*256+k][n] * Bm[c*256+s][n]
// ---------------------------------------------------------------------------
__global__ __launch_bounds__(256) void gmat_kernel(
    const bf16* __restrict__ Cm, const bf16* __restrict__ Bm,
    bf16* __restrict__ G) {
  const int c = blockIdx.x, kt = blockIdx.y, st = blockIdx.z;
  const int tid = threadIdx.x;
  const int wave = tid >> 6, lane = tid & 63;
  const int lrow = lane & 15, lk = (lane >> 4) * 8;
  const int wr = (wave >> 1) * 64, wc = (wave & 1) * 64;
  f32x4 acc[4][4] = {};
  for (int kk = 0; kk < 4; ++kk) {
    bf16x8 aF[4], bF[4];
    for (int m = 0; m < 4; ++m)
      aF[m] = *(const bf16x8*)(Cm + (size_t)(c * 256 + kt * 128 + wr + m * 16 + lrow) * 128 + kk * 32 + lk);
    for (int n = 0; n < 4; ++n)
      bF[n] = *(const bf16x8*)(Bm + (size_t)(c * 256 + st * 128 + wc + n * 16 + lrow) * 128 + kk * 32 + lk);
    for (int m = 0; m < 4; ++m)
      for (int n = 0; n < 4; ++n)
        acc[m][n] = mfma16(aF[m], bF[n], acc[m][n]);
  }
  const int orow = (lane >> 4) * 4;
  for (int m = 0; m < 4; ++m)
    for (int n = 0; n < 4; ++n)
      for (int i = 0; i < 4; ++i) {
        int k = kt * 128 + wr + m * 16 + orow + i;
        int s = st * 128 + wc + n * 16 + lrow;
        G[((size_t)c * 256 + k) * 256 + s] = (bf16)acc[m][n][i];
      }
}

// ---------------------------------------------------------------------------
__global__ __launch_bounds__(256) void states_kernel(
    const bf16* __restrict__ XDT_T, const bf16* __restrict__ BT,
    const float* __restrict__ decayO, float* __restrict__ states) {
  const int c = blockIdx.x, h = blockIdx.y;
  __shared__ bf16 Ap[64 * 264];
  __shared__ float sDec[256];
  const int tid = threadIdx.x;
  const int wave = tid >> 6, lane = tid & 63;
  const int lrow = lane & 15, lk = (lane >> 4) * 8;
  sDec[tid] = decayO[(size_t)(c * 64 + h) * 256 + tid];
  __syncthreads();
  {
    int p = tid >> 2, kb = (tid & 3) * 64;
    const bf16* src = XDT_T + (size_t)(h * 64 + p) * 4096 + c * 256 + kb;
    for (int j = 0; j < 8; ++j) {
      bf16x8 v = *(const bf16x8*)(src + j * 8);
      bf16x8 o;
      for (int i = 0; i < 8; ++i) o[i] = (bf16)((float)v[i] * sDec[kb + j * 8 + i]);
      *(bf16x8*)(Ap + p * 264 + kb + j * 8) = o;
    }
  }
  __syncthreads();
  const int nb = wave * 32;
  f32x4 acc[4][2] = {};
  for (int kk = 0; kk < 8; ++kk) {
    bf16x8 aF[4], bF[2];
    for (int m = 0; m < 4; ++m)
      aF[m] = *(const bf16x8*)(Ap + (m * 16 + lrow) * 264 + kk * 32 + lk);
    for (int n = 0; n < 2; ++n)
      bF[n] = *(const bf16x8*)(BT + (size_t)(nb + n * 16 + lrow) * 4096 + c * 256 + kk * 32 + lk);
    for (int m = 0; m < 4; ++m)
      for (int n = 0; n < 2; ++n)
        acc[m][n] = mfma16(aF[m], bF[n], acc[m][n]);
  }
  float* st = states + (size_t)(c * 64 + h) * 64 * 128;
  const int orow = (lane >> 4) * 4;
  for (int m = 0; m < 4; ++m)
    for (int n = 0; n < 2; ++n)
      for (int i = 0; i < 4; ++i)
        st[(size_t)(m * 16 + orow + i) * 128 + nb + n * 16 + lrow] = acc[m][n][i];
}

// ---------------------------------------------------------------------------
__global__ __launch_bounds__(128) void chunk_rec_kernel(
    const float* __restrict__ states, const float* __restrict__ csum,
    bf16* __restrict__ prev) {
  const int h = blockIdx.x, p = blockIdx.y;
  const int n = threadIdx.x;
  size_t base = (size_t)h * 64 * 128 + (size_t)p * 128 + n;
  float run = 0.f;
  for (int c = 0; c < 16; ++c) {
    size_t idx = (size_t)c * 64 * 64 * 128 + base;
    prev[idx] = (bf16)run;
    run = run * __expf(csum[c * 64 + h]) + states[idx];
  }
}

// ---------------------------------------------------------------------------
// Y = Y_off + Y_diag per (chunk, head).  (XS*D folded into rmsnorm.)
// G is bf16; per s-tile all fragment G loads batch-issued (single b128 each)
// before the exp/MFMA pass -- removes the serial gather->exp->MFMA chains.
// ---------------------------------------------------------------------------
__global__ __launch_bounds__(256) void ydiag_kernel(
    const bf16* __restrict__ Cm, const bf16* __restrict__ prev,
    const bf16* __restrict__ Gb, const float* __restrict__ Acs,
    const float* __restrict__ expAcs, const bf16* __restrict__ XDT_T,
    float* __restrict__ Y) {
  const int c = blockIdx.x, h = blockIdx.y;
  __shared__ float sAcs[256];
  __shared__ float sExp[256];
  __shared__ __align__(16) bf16 pv[64 * 136];
  __shared__ __align__(16) bf16 xd[64 * 264];
  const int tid = threadIdx.x;
  const int wave = tid >> 6, lane = tid & 63;
  const int lrow = lane & 15, lk = (lane >> 4) * 8;
  const int wv16 = wave * 16;
  sAcs[tid] = Acs[(size_t)(c * 64 + h) * 256 + tid];
  sExp[tid] = expAcs[(size_t)(c * 64 + h) * 256 + tid];
  {
    int r = tid >> 2, q = (tid & 3) * 32;
    const bf16* src = prev + (size_t)(c * 64 + h) * 8192 + r * 128 + q;
    bf16* dst = pv + r * 136 + q;
    for (int j = 0; j < 4; ++j)
      *(bf16x8*)(dst + j * 8) = *(const bf16x8*)(src + j * 8);
  }
  {
    int r = tid >> 2, q = (tid & 3) * 64;
    const bf16* src = XDT_T + (size_t)(h * 64 + r) * 4096 + c * 256 + q;
    bf16* dst = xd + r * 264 + q;
    for (int j = 0; j < 8; ++j)
      *(bf16x8*)(dst + j * 8) = *(const bf16x8*)(src + j * 8);
  }
  __syncthreads();
  f32x4 acc[4][4] = {};
  // --- Y_off: hoist all 16 Cm A-frag loads, then MFMA against pv (LDS) ---
  bf16x8 aYo[4][4];
#pragma unroll
  for (int kk = 0; kk < 4; ++kk)
#pragma unroll
    for (int m = 0; m < 4; ++m)
      aYo[kk][m] = *(const bf16x8*)(Cm + (size_t)(c * 256 + m * 64 + wv16 + lrow) * 128 + kk * 32 + lk);
#pragma unroll
  for (int kk = 0; kk < 4; ++kk) {
    bf16x8 bF[4];
#pragma unroll
    for (int n = 0; n < 4; ++n)
      bF[n] = *(const bf16x8*)(pv + (n * 16 + lrow) * 136 + kk * 32 + lk);
#pragma unroll
    for (int m = 0; m < 4; ++m)
#pragma unroll
      for (int n = 0; n < 4; ++n)
        acc[m][n] = mfma16(aYo[kk][m], bF[n], acc[m][n]);
  }
  const int orow = (lane >> 4) * 4;
#pragma unroll
  for (int m = 0; m < 4; ++m)
#pragma unroll
    for (int i = 0; i < 4; ++i) {
      float e = sExp[m * 64 + wv16 + orow + i];
      for (int n = 0; n < 4; ++n) acc[m][n][i] *= e;
    }
  // --- Y_diag: per s-tile, batch G loads -> registers, then exp+MFMA ---
  const bf16* Gp = Gb + (size_t)c * 65536;
#pragma unroll
  for (int stile = 0; stile < 4; ++stile) {
    const int s0 = stile * 64;
    bf16x8 graw[2][4];
#pragma unroll
    for (int kk = 0; kk < 2; ++kk)
#pragma unroll
      for (int m = 0; m < 4; ++m)
        if (m * 64 + wv16 + 15 >= s0) {
          int row = m * 64 + wv16 + lrow;
          graw[kk][m] = *(const bf16x8*)(Gp + (size_t)row * 256 + s0 + kk * 32 + lk);
        }
    bf16x8 bF[2][4];
#pragma unroll
    for (int kk = 0; kk < 2; ++kk)
#pragma unroll
      for (int n = 0; n < 4; ++n)
        bF[kk][n] = *(const bf16x8*)(xd + (n * 16 + lrow) * 264 + s0 + kk * 32 + lk);
#pragma unroll
    for (int kk = 0; kk < 2; ++kk)
#pragma unroll
      for (int m = 0; m < 4; ++m) {
        if (m * 64 + wv16 + 15 < s0) continue;
        const int row = m * 64 + wv16 + lrow;
        const float ak = sAcs[row];
        bf16x8 af;
#pragma unroll
        for (int j = 0; j < 8; ++j) {
          int s = s0 + kk * 32 + lk + j;
          float v = (float)graw[kk][m][j] * __expf(ak - sAcs[s]);
          if (s > row) v = 0.f;
          af[j] = (bf16)v;
        }
#pragma unroll
        for (int n = 0; n < 4; ++n)
          acc[m][n] = mfma16(af, bF[kk][n], acc[m][n]);
      }
  }
  // --- epilogue: write Y (f32), no XS here ---
#pragma unroll
  for (int m = 0; m < 4; ++m)
#pragma unroll
    for (int n = 0; n < 4; ++n)
#pragma unroll
      for (int i = 0; i < 4; ++i) {
        int t = c * 256 + m * 64 + wv16 + orow + i;
        int col = h * 64 + n * 16 + lrow;
        Y[(size_t)t * 4096 + col] = acc[m][n][i];
      }
}

// ---------------------------------------------------------------------------
// RMSNorm fused with + XS*D:  y = Y + XS*D[h];  out = y*rsqrt(mean(y^2))*w
// ---------------------------------------------------------------------------
__global__ __launch_bounds__(256) void rmsnorm_kernel(
    const float* __restrict__ Y, const bf16* __restrict__ XS,
    const float* __restrict__ Dp, const float* __restrict__ norm_w,
    bf16* __restrict__ out) {
  const int row = blockIdx.x;
  const float4* y4 = (const float4*)(Y + (size_t)row * 4096);
  const bf16x4* xs4 = (const bf16x4*)(XS + (size_t)row * 4096);
  float4 v[4];
  float ss = 0.f;
  for (int j = 0; j < 4; ++j) {
    int c4 = threadIdx.x + j * 256;
    float4 y = y4[c4];
    bf16x4 xs = xs4[c4];
    float d = Dp[(c4 * 4) >> 6];
    y.x += (float)xs[0] * d;
    y.y += (float)xs[1] * d;
    y.z += (float)xs[2] * d;
    y.w += (float)xs[3] * d;
    v[j] = y;
    ss += y.x * y.x + y.y * y.y + y.z * y.z + y.w * y.w;
  }
  for (int off = 32; off; off >>= 1) ss += __shfl_down(ss, off, 64);
  __shared__ float ws[4];
  if ((threadIdx.x & 63) == 0) ws[threadIdx.x >> 6] = ss;
  __syncthreads();
  float scale = rsqrtf((ws[0] + ws[1] + ws[2] + ws[3]) / 4096.f + 1e-6f);
  for (int j = 0; j < 4; ++j) {
    int col = (threadIdx.x + j * 256) * 4;
    float4 w = *(const float4*)(norm_w + col);
    bf16x4 o = {(bf16)(v[j].x * scale * w.x), (bf16)(v[j].y * scale * w.y),
                (bf16)(v[j].z * scale * w.z), (bf16)(v[j].w * scale * w.w)};
    *(bf16x4*)(out + (size_t)row * 4096 + col) = o;
  }
}

// ---------------------------------------------------------------------------
extern "C" void kernel_launch(void* const* d_in, const int* in_sizes, int n_in,
                              void* d_out, int out_size, void* d_ws, size_t ws_size,
                              hipStream_t stream) {
  const float* x       = (const float*)d_in[0];
  const float* W_in    = (const float*)d_in[1];
  const float* conv_w  = (const float*)d_in[2];
  const float* conv_b  = (const float*)d_in[3];
  const float* dt_bias = (const float*)d_in[4];
  const float* A_log   = (const float*)d_in[5];
  const float* Dp      = (const float*)d_in[6];
  const float* norm_w  = (const float*)d_in[7];
  const float* W_out   = (const float*)d_in[8];

  size_t o = 0;
  char* base = (char*)d_ws;
  auto take = [&](size_t b) {
    char* p = base + o;
    o += (b + 255) & ~(size_t)255;
    return (void*)p;
  };
  bf16*  xb     = (bf16*)take((size_t)4096 * 2048 * 2);    // 16.8 MB
  bf16*  winb   = (bf16*)take((size_t)4608 * 2048 * 2);    // 18.9 MB
  bf16*  xp0b   = (bf16*)take((size_t)4096 * 4608 * 2);    // 37.75 MB
  bf16*  xp1b   = (bf16*)take((size_t)4096 * 4608 * 2);    // 37.75 MB
  float* dt0    = (float*)take((size_t)4096 * 64 * 4);
  float* dt1    = (float*)take((size_t)4096 * 64 * 4);
  float* dtg    = (float*)take((size_t)4096 * 64 * 4);
  float* Acs    = (float*)take((size_t)4096 * 64 * 4);
  float* decayO = (float*)take((size_t)4096 * 64 * 4);
  float* expA   = (float*)take((size_t)4096 * 64 * 4);
  float* csum   = (float*)take((size_t)16 * 64 * 4);
  bf16*  XS     = (bf16*)take((size_t)4096 * 4096 * 2);    // 33.6 MB
  bf16*  XDT_T  = (bf16*)take((size_t)4096 * 4096 * 2);    // 33.6 MB
  bf16*  Bm     = (bf16*)take((size_t)4096 * 128 * 2);
  bf16*  BT     = (bf16*)take((size_t)4096 * 128 * 2);
  bf16*  Cm     = (bf16*)take((size_t)4096 * 128 * 2);
  float* Y      = (float*)take((size_t)4096 * 4096 * 4);   // 67.1 MB
  // aliases into xp0b/xp1b (dead after conv): Gb | states | prev | woutb
  bf16*  Gb     = (bf16*)((char*)xp0b);                         // 2.10 MB
  float* states = (float*)((char*)xp0b + (size_t)4194304);      // 33.55 MB
  bf16*  prev   = (bf16*)((char*)xp0b + (size_t)37748736);      // 16.78 MB
  bf16*  woutb  = (bf16*)((char*)xp0b + (size_t)54525952);      // 16.78 MB
  bf16*  ynorm  = xb;             // xb+winb dead after GEMM1; 33.6 <= 35.7
  bf16*  p2a    = XS;             // XS dead after rmsnorm
  bf16*  p2b    = XDT_T;          // XDT dead after ydiag

  // 1) casts for GEMM1
  cast_f2b_kernel<<<2048, 256, 0, stream>>>(x, xb, (long)4096 * 2048 / 4);
  cast_pad_kernel<<<2048, 256, 0, stream>>>(W_in, winb, (long)4608 * 2048 / 4,
                                            (long)4416 * 2048 / 4);
  // 2) GEMM1 split-K2 -> bf16 partials + f32 dt side-channel (K half 1024)
  gemm_kernel<32, 2048, true><<<dim3(288, 2), 512, 0, stream>>>(
      xb, winb, xp0b, xp1b, dt0, dt1, 4608, 18);
  // 3) dt + per-chunk cumsum
  dt_scan_kernel<<<dim3(16, 64), 256, 0, stream>>>(dt0, dt1, dt_bias, A_log,
                                                   dtg, Acs, decayO, expA, csum);
  // 4) conv + silu + layout builds
  conv_kernel<<<dim3(64, 68), 256, 0, stream>>>(xp0b, xp1b, conv_w, conv_b, dtg,
                                                XS, XDT_T, Bm, BT, Cm);
  // 5) G = C @ B^T per chunk (bf16; xp0b/xp1b now dead -> aliases live there)
  gmat_kernel<<<dim3(16, 2, 2), 256, 0, stream>>>(Cm, Bm, Gb);
  // 6) intra-chunk states
  states_kernel<<<dim3(16, 64), 256, 0, stream>>>(XDT_T, BT, decayO, states);
  // 7) inter-chunk recurrence -> prev (bf16)
  chunk_rec_kernel<<<dim3(64, 64), 128, 0, stream>>>(states, csum, prev);
  // 8) W_out cast
  cast_f2b_kernel<<<2048, 256, 0, stream>>>(W_out, woutb, (long)2048 * 4096 / 4);
  // 9) Y = Y_diag + Y_off
  ydiag_kernel<<<dim3(16, 64), 256, 0, stream>>>(Cm, prev, Gb, Acs, expA,
                                                 XDT_T, Y);
  // 10) RMSNorm (fused + XS*D) -> bf16
  rmsnorm_kernel<<<4096, 256, 0, stream>>>(Y, XS, Dp, norm_w, ynorm);
  // 11) GEMM2 split-K2 -> bf16 partials (K half 2048)
  gemm_kernel<64, 4096, false><<<dim3(128, 2), 512, 0, stream>>>(
      ynorm, woutb, p2a, p2b, nullptr, nullptr, 2048, 8);
  // 12) out = p2a + p2b (f32)
  add2b_kernel<<<2048, 256, 0, stream>>>(p2a, p2b, (float*)d_out,
                                         (long)4096 * 2048 / 8);
}